// Round 8
// baseline (801.509 us; speedup 1.0000x reference)
//
#include <hip/hip_runtime.h>
#include <hip/hip_bf16.h>
#include <stdint.h>

#define NTOK 49
#define LOG2E 1.4426950408889634f
#define SCALE2 0.25507662683243807f   /* 32^-0.5 * log2(e) */

typedef __attribute__((ext_vector_type(4))) float f32x4;
typedef __attribute__((ext_vector_type(2))) unsigned int u32x2;
typedef __attribute__((ext_vector_type(4))) unsigned int u32x4;
typedef __attribute__((ext_vector_type(8))) short bfrag;
typedef __attribute__((ext_vector_type(4))) short s16x4;
typedef __attribute__((ext_vector_type(4))) float facc;

#define MFMA16(A,B,C) __builtin_amdgcn_mfma_f32_16x16x32_bf16(A,B,C,0,0,0)
#define EXP2(x) __builtin_amdgcn_exp2f(x)

__device__ __forceinline__ unsigned pk2bf(float a, float b) {
    unsigned r;
    asm("v_cvt_pk_bf16_f32 %0, %1, %2" : "=v"(r) : "v"(a), "v"(b));
    return r;
}
__device__ __forceinline__ short f2bf(float a) {
    unsigned ua = __builtin_bit_cast(unsigned, a);
    ua = ua + 0x7fffu + ((ua >> 16) & 1u);
    return (short)(ua >> 16);
}
__device__ __forceinline__ float bf2f(short s) {
    unsigned u = ((unsigned)(unsigned short)s) << 16;
    return __builtin_bit_cast(float, u);
}
__device__ __forceinline__ int sw256(int row, int cb) { return row * 256 + (cb ^ ((row & 7) << 4)); }
__device__ __forceinline__ int strip64(int row, int cb) { return row * 64 + (cb ^ (((row >> 1) & 3) << 4)); }
__device__ __forceinline__ int sw128v(int row, int cb) { return row * 128 + (cb ^ ((row & 7) << 4)); }

__global__ void prep_w(const float* __restrict__ Wq, const float* __restrict__ Wk,
                       const float* __restrict__ Wv, const float* __restrict__ Wp,
                       const float* __restrict__ relb, short* __restrict__ ws)
{
    int t = blockIdx.x * 256 + threadIdx.x;
    if (t >= 16384) return;
    int e = t & 7, lane = (t >> 3) & 63, ks = (t >> 9) & 3, tile = t >> 11;
    int row = tile * 16 + (lane & 15);
    int col = ks * 32 + (lane >> 4) * 8 + e;
    int src = row * 128 + col;
    ws[t]         = f2bf(Wq[src]);
    ws[16384 + t] = f2bf(Wk[src]);
    ws[32768 + t] = f2bf(Wv[src]);
    ws[49152 + t] = f2bf(Wp[src]);
    int e2 = t & 3, lane2 = (t >> 2) & 63, mt = (t >> 8) & 3, rt = (t >> 10) & 3, h = t >> 12;
    int r = rt * 16 + (lane2 & 15);
    int m = mt * 16 + (lane2 >> 4) * 4 + e2;
    float v = 0.f;
    if (r < NTOK && m < NTOK) {
        int idx = ((r / 7 - m / 7) + 6) * 13 + ((r % 7) - (m % 7) + 6);
        v = relb[idx * 4 + h] * LOG2E;
    }
    ws[65536 + t] = f2bf(v);
}

__global__ void prep_cmb(const float* __restrict__ mask, const float* __restrict__ relb,
                         short* __restrict__ cmb)
{
    int t = blockIdx.x * 256 + threadIdx.x;
    int e = t & 3, lane = (t >> 2) & 63, mt = (t >> 8) & 3, rt = (t >> 10) & 3;
    int h = (t >> 12) & 3, w = t >> 14;
    int r = rt * 16 + (lane & 15);
    int m = mt * 16 + (lane >> 4) * 4 + e;
    float v = -1e30f;
    if (r < NTOK && m < NTOK) {
        int idx = ((r / 7 - m / 7) + 6) * 13 + ((r % 7) - (m % 7) + 6);
        v = (mask[w * (NTOK * NTOK) + r * NTOK + m] + relb[idx * 4 + h]) * LOG2E;
    }
    cmb[t] = f2bf(v);
}

// persistent: 768 blocks (3/CU, 48K LDS) × 21-22 windows.
// LDS: x[64][256B] @0 | per-wave 8K scratch @16K+wid*8K
//   scratch[0-4K]: q-strip -> k-strip -> P halves (wave-private, in-wave DS order)
//   scratch[4-8K]: vT[32][128B]
//   att[64][256B] overlays waves 0/1 scratch after B1.
__global__ __launch_bounds__(256, 3) void swin_fwd_p(
    const float* __restrict__ x,
    const float* __restrict__ bq, const float* __restrict__ bk,
    const float* __restrict__ bv, const float* __restrict__ bp,
    const short* __restrict__ wqf, const short* __restrict__ wkf,
    const short* __restrict__ wvf, const short* __restrict__ wpf,
    const short* __restrict__ cmbf, float* __restrict__ out)
{
    extern __shared__ char smem[];
    char* xbuf = smem;
    char* attb = smem + 16384;

    const int b = blockIdx.x;
    const int tid = threadIdx.x;
    const int wid = tid >> 6;
    const int lane = tid & 63;
    const int l16 = lane & 15;
    const int lg = lane >> 4;
    char* wscr = smem + 16384 + wid * 8192;
    const int cnt = (b < 256) ? 22 : 21;

    float bqv[2][4], bkv[2][4], bpv[2][4], bvv2[2];
    #pragma unroll
    for (int mt = 0; mt < 2; ++mt) {
        #pragma unroll
        for (int j = 0; j < 4; ++j) {
            int o = wid * 32 + mt * 16 + lg * 4 + j;
            bqv[mt][j] = bq[o]; bkv[mt][j] = bk[o]; bpv[mt][j] = bp[o];
        }
        bvv2[mt] = bv[wid * 32 + mt * 16 + l16];
    }

    bfrag aq[2][4], ak[2][4], av[2][4];
    {
        const short* wq_i = wqf; const short* wk_i = wkf; const short* wv_i = wvf;
        asm volatile("" : "+s"(wq_i), "+s"(wk_i), "+s"(wv_i));
        #pragma unroll
        for (int mt = 0; mt < 2; ++mt)
            #pragma unroll
            for (int ks = 0; ks < 4; ++ks) {
                int fi = (((wid * 2 + mt) * 4 + ks) * 64 + lane) * 8;
                aq[mt][ks] = *(const bfrag*)(wq_i + fi);
                ak[mt][ks] = *(const bfrag*)(wk_i + fi);
                av[mt][ks] = *(const bfrag*)(wv_i + fi);
            }
    }

    f32x4 xr[7];
    {
        const float* xw0 = x + (size_t)b * 6272;
        #pragma unroll
        for (int ii = 0; ii < 7; ++ii) {
            int i4 = ii * 256 + tid;
            if (i4 < 1568) xr[ii] = *(const f32x4*)(xw0 + i4 * 4);
        }
        #pragma unroll
        for (int ii = 0; ii < 7; ++ii) {
            int i4 = ii * 256 + tid;
            if (i4 < 1568) {
                int tok = i4 >> 5, col = (i4 & 31) * 4;
                u32x2 w; w.x = pk2bf(xr[ii].x, xr[ii].y); w.y = pk2bf(xr[ii].z, xr[ii].w);
                *(u32x2*)(xbuf + sw256(tok, col * 2)) = w;
            }
        }
        if (tid < 240) { u32x4 z = {0, 0, 0, 0}; *(u32x4*)(xbuf + 49 * 256 + tid * 16) = z; }
    }
    __syncthreads();

    #pragma unroll 1
    for (int it = 0; it < cnt; ++it) {
        const int win = b + it * 768;

        u32x2 kp[4][2];
        {
            #pragma unroll
            for (int nt = 0; nt < 4; ++nt) {
                bfrag bx[4];
                #pragma unroll
                for (int ks = 0; ks < 4; ++ks)
                    bx[ks] = *(const bfrag*)(xbuf + sw256(nt * 16 + l16, (ks * 32 + lg * 8) * 2));
                facc accq[2] = {{0,0,0,0},{0,0,0,0}};
                facc acck[2] = {{0,0,0,0},{0,0,0,0}};
                facc accv[2] = {{0,0,0,0},{0,0,0,0}};
                __builtin_amdgcn_s_setprio(1);
                #pragma unroll
                for (int ks = 0; ks < 4; ++ks)
                    #pragma unroll
                    for (int mt = 0; mt < 2; ++mt) {
                        accq[mt] = MFMA16(aq[mt][ks], bx[ks], accq[mt]);
                        acck[mt] = MFMA16(ak[mt][ks], bx[ks], acck[mt]);
                        accv[mt] = MFMA16(bx[ks], av[mt][ks], accv[mt]);
                    }
                __builtin_amdgcn_s_setprio(0);
                int tok = nt * 16 + l16;
                #pragma unroll
                for (int mt = 0; mt < 2; ++mt) {
                    u32x2 wq2, wv2;
                    wq2.x = pk2bf((accq[mt][0] + bqv[mt][0]) * SCALE2, (accq[mt][1] + bqv[mt][1]) * SCALE2);
                    wq2.y = pk2bf((accq[mt][2] + bqv[mt][2]) * SCALE2, (accq[mt][3] + bqv[mt][3]) * SCALE2);
                    *(u32x2*)(wscr + strip64(tok, mt * 32 + lg * 8)) = wq2;
                    kp[nt][mt].x = pk2bf(acck[mt][0] + bkv[mt][0], acck[mt][1] + bkv[mt][1]);
                    kp[nt][mt].y = pk2bf(acck[mt][2] + bkv[mt][2], acck[mt][3] + bkv[mt][3]);
                    wv2.x = pk2bf(accv[mt][0] + bvv2[mt], accv[mt][1] + bvv2[mt]);
                    wv2.y = pk2bf(accv[mt][2] + bvv2[mt], accv[mt][3] + bvv2[mt]);
                    *(u32x2*)(wscr + 4096 + sw128v(mt * 16 + l16, nt * 32 + lg * 8)) = wv2;
                }
            }
        }
        bfrag qb[4];
        #pragma unroll
        for (int t = 0; t < 4; ++t)
            qb[t] = *(const bfrag*)(wscr + strip64(t * 16 + l16, lg * 16));
        #pragma unroll
        for (int nt = 0; nt < 4; ++nt)
            #pragma unroll
            for (int mt = 0; mt < 2; ++mt)
                *(u32x2*)(wscr + strip64(nt * 16 + l16, mt * 32 + lg * 8)) = kp[nt][mt];
        bfrag ka[4];
        #pragma unroll
        for (int t = 0; t < 4; ++t)
            ka[t] = *(const bfrag*)(wscr + strip64(t * 16 + l16, lg * 16));

        s16x4 b4r[4][4];
        {
            const short* cw = cmbf + ((size_t)((win & 1023) * 4 + wid) << 12);
            #pragma unroll
            for (int rt = 0; rt < 4; ++rt)
                #pragma unroll
                for (int mt = 0; mt < 4; ++mt)
                    b4r[rt][mt] = *(const s16x4*)(cw + ((rt * 4 + mt) << 8) + lane * 4);
        }

        facc s[4][4];
        {
            __builtin_amdgcn_s_setprio(1);
            #pragma unroll
            for (int mt = 0; mt < 4; ++mt)
                #pragma unroll
                for (int rt = 0; rt < 4; ++rt) {
                    facc z = {0, 0, 0, 0};
                    s[mt][rt] = MFMA16(ka[mt], qb[rt], z);
                }
            __builtin_amdgcn_s_setprio(0);
        }

        if (it + 1 < cnt) {
            const float* xn = x + (size_t)(win + 768) * 6272;
            #pragma unroll
            for (int ii = 0; ii < 7; ++ii) {
                int i4 = ii * 256 + tid;
                if (i4 < 1568) xr[ii] = *(const f32x4*)(xn + i4 * 4);
            }
        }

        float rs4[4];
        u32x2 pwB[4][2];
        {
            #pragma unroll
            for (int rt = 0; rt < 4; ++rt) {
                float lgt[4][4];
                float mx = -3e38f;
                #pragma unroll
                for (int mt = 0; mt < 4; ++mt)
                    #pragma unroll
                    for (int j = 0; j < 4; ++j) {
                        float v = s[mt][rt][j] + bf2f(b4r[rt][mt][j]);
                        lgt[mt][j] = v;
                        mx = fmaxf(mx, v);
                    }
                mx = fmaxf(mx, __shfl_xor(mx, 16));
                mx = fmaxf(mx, __shfl_xor(mx, 32));
                float sum = 0.f;
                u32x2 pw[4];
                #pragma unroll
                for (int mt = 0; mt < 4; ++mt) {
                    float p0 = EXP2(lgt[mt][0] - mx);
                    float p1 = EXP2(lgt[mt][1] - mx);
                    float p2 = EXP2(lgt[mt][2] - mx);
                    float p3 = EXP2(lgt[mt][3] - mx);
                    sum += (p0 + p1) + (p2 + p3);
                    pw[mt].x = pk2bf(p0, p1);
                    pw[mt].y = pk2bf(p2, p3);
                }
                sum += __shfl_xor(sum, 16);
                sum += __shfl_xor(sum, 32);
                rs4[rt] = __builtin_amdgcn_rcpf(sum);
                int r = rt * 16 + l16;
                *(u32x2*)(wscr + strip64(r, lg * 8)) = pw[0];
                *(u32x2*)(wscr + strip64(r, 32 + lg * 8)) = pw[1];
                pwB[rt][0] = pw[2]; pwB[rt][1] = pw[3];
            }
        }

        facc o2[2][4];
        #pragma unroll
        for (int ct = 0; ct < 2; ++ct)
            #pragma unroll
            for (int rt = 0; rt < 4; ++rt) o2[ct][rt] = (facc){0, 0, 0, 0};
        {
            bfrag avf[2], pb[4];
            #pragma unroll
            for (int ct = 0; ct < 2; ++ct)
                avf[ct] = *(const bfrag*)(wscr + 4096 + sw128v(ct * 16 + l16, lg * 16));
            #pragma unroll
            for (int rt = 0; rt < 4; ++rt)
                pb[rt] = *(const bfrag*)(wscr + strip64(rt * 16 + l16, lg * 16));
            __builtin_amdgcn_s_setprio(1);
            #pragma unroll
            for (int ct = 0; ct < 2; ++ct)
                #pragma unroll
                for (int rt = 0; rt < 4; ++rt)
                    o2[ct][rt] = MFMA16(avf[ct], pb[rt], o2[ct][rt]);
            __builtin_amdgcn_s_setprio(0);
        }
        #pragma unroll
        for (int rt = 0; rt < 4; ++rt) {
            int r = rt * 16 + l16;
            *(u32x2*)(wscr + strip64(r, lg * 8)) = pwB[rt][0];
            *(u32x2*)(wscr + strip64(r, 32 + lg * 8)) = pwB[rt][1];
        }
        {
            bfrag avf[2], pb[4];
            #pragma unroll
            for (int ct = 0; ct < 2; ++ct)
                avf[ct] = *(const bfrag*)(wscr + 4096 + sw128v(ct * 16 + l16, 64 + lg * 16));
            #pragma unroll
            for (int rt = 0; rt < 4; ++rt)
                pb[rt] = *(const bfrag*)(wscr + strip64(rt * 16 + l16, lg * 16));
            __builtin_amdgcn_s_setprio(1);
            #pragma unroll
            for (int ct = 0; ct < 2; ++ct)
                #pragma unroll
                for (int rt = 0; rt < 4; ++rt)
                    o2[ct][rt] = MFMA16(avf[ct], pb[rt], o2[ct][rt]);
            __builtin_amdgcn_s_setprio(0);
        }
        u32x2 attw[2][4];
        #pragma unroll
        for (int ct = 0; ct < 2; ++ct)
            #pragma unroll
            for (int rt = 0; rt < 4; ++rt) {
                float sc = rs4[rt];
                attw[ct][rt].x = pk2bf(o2[ct][rt][0] * sc, o2[ct][rt][1] * sc);
                attw[ct][rt].y = pk2bf(o2[ct][rt][2] * sc, o2[ct][rt][3] * sc);
            }
        bfrag ap[2][4];
        {
            const short* wp_i = wpf;
            asm volatile("" : "+s"(wp_i));
            #pragma unroll
            for (int mt = 0; mt < 2; ++mt)
                #pragma unroll
                for (int ks = 0; ks < 4; ++ks)
                    ap[mt][ks] = *(const bfrag*)(wp_i + (((wid * 2 + mt) * 4 + ks) * 64 + lane) * 8);
        }
        __syncthreads();   // B1
        #pragma unroll
        for (int ct = 0; ct < 2; ++ct)
            #pragma unroll
            for (int rt = 0; rt < 4; ++rt)
                *(u32x2*)(attb + sw256(rt * 16 + l16, (wid * 32 + ct * 16 + lg * 4) * 2)) = attw[ct][rt];
        if (it + 1 < cnt) {
            #pragma unroll
            for (int ii = 0; ii < 7; ++ii) {
                int i4 = ii * 256 + tid;
                if (i4 < 1568) {
                    int tok = i4 >> 5, col = (i4 & 31) * 4;
                    u32x2 w; w.x = pk2bf(xr[ii].x, xr[ii].y); w.y = pk2bf(xr[ii].z, xr[ii].w);
                    *(u32x2*)(xbuf + sw256(tok, col * 2)) = w;
                }
            }
        }
        __syncthreads();   // B2

        {
            facc acco[2][4];
            #pragma unroll
            for (int mt = 0; mt < 2; ++mt)
                #pragma unroll
                for (int tt = 0; tt < 4; ++tt) acco[mt][tt] = (facc){0, 0, 0, 0};
            #pragma unroll
            for (int tt = 0; tt < 4; ++tt) {
                bfrag ba[4];
                #pragma unroll
                for (int ks = 0; ks < 4; ++ks)
                    ba[ks] = *(const bfrag*)(attb + sw256(tt * 16 + l16, (ks * 32 + lg * 8) * 2));
                __builtin_amdgcn_s_setprio(1);
                #pragma unroll
                for (int ks = 0; ks < 4; ++ks)
                    #pragma unroll
                    for (int mt = 0; mt < 2; ++mt)
                        acco[mt][tt] = MFMA16(ap[mt][ks], ba[ks], acco[mt][tt]);
                __builtin_amdgcn_s_setprio(0);
            }
            float* ow = out + (size_t)win * 6272;
            #pragma unroll
            for (int tt = 0; tt < 4; ++tt) {
                int tok = tt * 16 + l16;
                if (tok < NTOK) {
                    #pragma unroll
                    for (int mt = 0; mt < 2; ++mt) {
                        int o0 = wid * 32 + mt * 16 + lg * 4;
                        f32x4 w;
                        w.x = acco[mt][tt][0] + bpv[mt][0];
                        w.y = acco[mt][tt][1] + bpv[mt][1];
                        w.z = acco[mt][tt][2] + bpv[mt][2];
                        w.w = acco[mt][tt][3] + bpv[mt][3];
                        *(f32x4*)(ow + tok * 128 + o0) = w;
                    }
                }
            }
        }
        {
            const short* wq_i = wqf; const short* wk_i = wkf; const short* wv_i = wvf;
            asm volatile("" : "+s"(wq_i), "+s"(wk_i), "+s"(wv_i));
            #pragma unroll
            for (int mt = 0; mt < 2; ++mt)
                #pragma unroll
                for (int ks = 0; ks < 4; ++ks) {
                    int fi = (((wid * 2 + mt) * 4 + ks) * 64 + lane) * 8;
                    aq[mt][ks] = *(const bfrag*)(wq_i + fi);
                    ak[mt][ks] = *(const bfrag*)(wk_i + fi);
                    av[mt][ks] = *(const bfrag*)(wv_i + fi);
                }
        }
        __syncthreads();   // B3
    }
}

// fallback (no cmb): round-6 structure, grid 16384
__global__ __launch_bounds__(256, 2) void swin_fwd_fb(
    const float* __restrict__ x, const float* __restrict__ mask,
    const float* __restrict__ bq, const float* __restrict__ bk,
    const float* __restrict__ bv, const float* __restrict__ bp,
    const short* __restrict__ wqf, const short* __restrict__ wkf,
    const short* __restrict__ wvf, const short* __restrict__ wpf,
    const short* __restrict__ rbf, float* __restrict__ out)
{
    extern __shared__ char smem[];
    char* qbuf  = smem;
    char* kbuf  = smem + 16384;
    char* vtbuf = smem + 32768;
    char* r4    = smem + 49152;

    const int win = blockIdx.x;
    const int tid = threadIdx.x;
    const int wid = tid >> 6;
    const int lane = tid & 63;
    const int l16 = lane & 15;
    const int lg = lane >> 4;

    {
        const float* xw = x + (size_t)win * 6272;
        #pragma unroll
        for (int i = 0; i < 7; ++i) {
            int i4 = i * 256 + tid;
            if (i4 < 1568) {
                f32x4 f = *(const f32x4*)(xw + i4 * 4);
                int tok = i4 >> 5, col = (i4 & 31) * 4;
                u32x2 w; w.x = pk2bf(f.x, f.y); w.y = pk2bf(f.z, f.w);
                *(u32x2*)(r4 + sw256(tok, col * 2)) = w;
            }
        }
        if (tid < 240) { u32x4 z = {0, 0, 0, 0}; *(u32x4*)(r4 + 49 * 256 + tid * 16) = z; }
    }
    bfrag aq[2][4], ak[2][4], av[2][4];
    float bqv[2][4], bkv[2][4], bvv2[2];
    #pragma unroll
    for (int mt = 0; mt < 2; ++mt) {
        #pragma unroll
        for (int ks = 0; ks < 4; ++ks) {
            int fi = (((wid * 2 + mt) * 4 + ks) * 64 + lane) * 8;
            aq[mt][ks] = *(const bfrag*)(wqf + fi);
            ak[mt][ks] = *(const bfrag*)(wkf + fi);
            av[mt][ks] = *(const bfrag*)(wvf + fi);
        }
        #pragma unroll
        for (int j = 0; j < 4; ++j) {
            int o = wid * 32 + mt * 16 + lg * 4 + j;
            bqv[mt][j] = bq[o]; bkv[mt][j] = bk[o];
        }
        bvv2[mt] = bv[wid * 32 + mt * 16 + l16];
    }
    __syncthreads();

    {
        #pragma unroll
        for (int nt = 0; nt < 4; ++nt) {
            bfrag bx[4];
            #pragma unroll
            for (int ks = 0; ks < 4; ++ks)
                bx[ks] = *(const bfrag*)(r4 + sw256(nt * 16 + l16, (ks * 32 + lg * 8) * 2));
            facc accq[2] = {{0,0,0,0},{0,0,0,0}};
            facc acck[2] = {{0,0,0,0},{0,0,0,0}};
            facc accv[2] = {{0,0,0,0},{0,0,0,0}};
            #pragma unroll
            for (int ks = 0; ks < 4; ++ks)
                #pragma unroll
                for (int mt = 0; mt < 2; ++mt) {
                    accq[mt] = MFMA16(aq[mt][ks], bx[ks], accq[mt]);
                    acck[mt] = MFMA16(ak[mt][ks], bx[ks], acck[mt]);
                    accv[mt] = MFMA16(bx[ks], av[mt][ks], accv[mt]);
                }
            int tok = nt * 16 + l16;
            #pragma unroll
            for (int mt = 0; mt < 2; ++mt) {
                int o0 = wid * 32 + mt * 16 + lg * 4;
                u32x2 wq2, wk2, wv2;
                wq2.x = pk2bf((accq[mt][0] + bqv[mt][0]) * SCALE2, (accq[mt][1] + bqv[mt][1]) * SCALE2);
                wq2.y = pk2bf((accq[mt][2] + bqv[mt][2]) * SCALE2, (accq[mt][3] + bqv[mt][3]) * SCALE2);
                wk2.x = pk2bf(acck[mt][0] + bkv[mt][0], acck[mt][1] + bkv[mt][1]);
                wk2.y = pk2bf(acck[mt][2] + bkv[mt][2], acck[mt][3] + bkv[mt][3]);
                *(u32x2*)(qbuf + sw256(tok, o0 * 2)) = wq2;
                *(u32x2*)(kbuf + sw256(tok, o0 * 2)) = wk2;
                wv2.x = pk2bf(accv[mt][0] + bvv2[mt], accv[mt][1] + bvv2[mt]);
                wv2.y = pk2bf(accv[mt][2] + bvv2[mt], accv[mt][3] + bvv2[mt]);
                *(u32x2*)(vtbuf + sw128v(wid * 32 + mt * 16 + l16, (nt * 16 + lg * 4) * 2)) = wv2;
            }
        }
    }
    facc s[4][4];
    {
        bfrag ka[4], qb[4];
        int cb = (wid * 32 + lg * 8) * 2;
        #pragma unroll
        for (int t = 0; t < 4; ++t) {
            ka[t] = *(const bfrag*)(kbuf + sw256(t * 16 + l16, cb));
            qb[t] = *(const bfrag*)(qbuf + sw256(t * 16 + l16, cb));
        }
        #pragma unroll
        for (int mt = 0; mt < 4; ++mt)
            #pragma unroll
            for (int rt = 0; rt < 4; ++rt) {
                facc z = {0, 0, 0, 0};
                s[mt][rt] = MFMA16(ka[mt], qb[rt], z);
            }
    }
    __syncthreads();
    {
        const float* mw = mask + (size_t)(win & 1023) * (NTOK * NTOK);
        #pragma unroll
        for (int i = 0; i < 16; ++i) {
            int flat = i * 256 + tid;
            int r = flat >> 6, m = flat & 63;
            float v = -1e30f;
            if (r < NTOK && m < NTOK) v = mw[r * 49 + m] * LOG2E;
            *(float*)(r4 + sw256(r, m * 4)) = v;
        }
    }
    __syncthreads();
    float rs4[4];
    {
        #pragma unroll
        for (int rt = 0; rt < 4; ++rt) {
            int r = rt * 16 + l16;
            float lgt[4][4];
            float mx = -3e38f;
            #pragma unroll
            for (int mt = 0; mt < 4; ++mt) {
                s16x4 b4 = *(const s16x4*)(rbf + ((wid * 16 + rt * 4 + mt) * 64 + lane) * 4);
                f32x4 mk = *(const f32x4*)(r4 + sw256(r, (mt * 16 + lg * 4) * 4));
                #pragma unroll
                for (int j = 0; j < 4; ++j) {
                    float v = s[mt][rt][j] + bf2f(b4[j]) + mk[j];
                    lgt[mt][j] = v;
                    mx = fmaxf(mx, v);
                }
            }
            mx = fmaxf(mx, __shfl_xor(mx, 16));
            mx = fmaxf(mx, __shfl_xor(mx, 32));
            float sum = 0.f;
            u32x2 pw[4];
            #pragma unroll
            for (int mt = 0; mt < 4; ++mt) {
                float p0 = EXP2(lgt[mt][0] - mx);
                float p1 = EXP2(lgt[mt][1] - mx);
                float p2 = EXP2(lgt[mt][2] - mx);
                float p3 = EXP2(lgt[mt][3] - mx);
                sum += (p0 + p1) + (p2 + p3);
                pw[mt].x = pk2bf(p0, p1);
                pw[mt].y = pk2bf(p2, p3);
            }
            sum += __shfl_xor(sum, 16);
            sum += __shfl_xor(sum, 32);
            rs4[rt] = __builtin_amdgcn_rcpf(sum);
            #pragma unroll
            for (int mt = 0; mt < 4; ++mt) {
                int mb = mt * 32 + lg * 8;
                *(u32x2*)(smem + ((mb >> 6) << 14) + r * 256 + ((wid * 64 + (mb & 63)) ^ ((r & 7) << 4))) = pw[mt];
            }
        }
    }
    facc o2[2][4];
    {
        #pragma unroll
        for (int ct = 0; ct < 2; ++ct)
            #pragma unroll
            for (int rt = 0; rt < 4; ++rt) o2[ct][rt] = (facc){0, 0, 0, 0};
        #pragma unroll
        for (int ks = 0; ks < 2; ++ks) {
            bfrag avf[2], pb[4];
            #pragma unroll
            for (int ct = 0; ct < 2; ++ct)
                avf[ct] = *(const bfrag*)(vtbuf + sw128v(wid * 32 + ct * 16 + l16, (ks * 32 + lg * 8) * 2));
            #pragma unroll
            for (int rt = 0; rt < 4; ++rt) {
                int mb = ks * 64 + lg * 16, r = rt * 16 + l16;
                pb[rt] = *(const bfrag*)(smem + ((mb >> 6) << 14) + r * 256 + ((wid * 64 + (mb & 63)) ^ ((r & 7) << 4)));
            }
            #pragma unroll
            for (int ct = 0; ct < 2; ++ct)
                #pragma unroll
                for (int rt = 0; rt < 4; ++rt)
                    o2[ct][rt] = MFMA16(avf[ct], pb[rt], o2[ct][rt]);
        }
    }
    bfrag ap[2][4];
    float bpv[2][4];
    #pragma unroll
    for (int mt = 0; mt < 2; ++mt) {
        #pragma unroll
        for (int ks = 0; ks < 4; ++ks)
            ap[mt][ks] = *(const bfrag*)(wpf + (((wid * 2 + mt) * 4 + ks) * 64 + lane) * 8);
        #pragma unroll
        for (int j = 0; j < 4; ++j)
            bpv[mt][j] = bp[wid * 32 + mt * 16 + lg * 4 + j];
    }
    __syncthreads();
    {
        #pragma unroll
        for (int ct = 0; ct < 2; ++ct) {
            int c0 = wid * 32 + ct * 16 + lg * 4;
            #pragma unroll
            for (int rt = 0; rt < 4; ++rt) {
                int r = rt * 16 + l16;
                float sc = rs4[rt];
                u32x2 w;
                w.x = pk2bf(o2[ct][rt][0] * sc, o2[ct][rt][1] * sc);
                w.y = pk2bf(o2[ct][rt][2] * sc, o2[ct][rt][3] * sc);
                *(u32x2*)(r4 + sw256(r, c0 * 2)) = w;
            }
        }
    }
    __syncthreads();
    {
        facc acco[2][4];
        #pragma unroll
        for (int mt = 0; mt < 2; ++mt)
            #pragma unroll
            for (int tt = 0; tt < 4; ++tt) acco[mt][tt] = (facc){0, 0, 0, 0};
        #pragma unroll
        for (int tt = 0; tt < 4; ++tt) {
            bfrag ba[4];
            #pragma unroll
            for (int ks = 0; ks < 4; ++ks)
                ba[ks] = *(const bfrag*)(r4 + sw256(tt * 16 + l16, (ks * 32 + lg * 8) * 2));
            #pragma unroll
            for (int ks = 0; ks < 4; ++ks)
                #pragma unroll
                for (int mt = 0; mt < 2; ++mt)
                    acco[mt][tt] = MFMA16(ap[mt][ks], ba[ks], acco[mt][tt]);
        }
        float* ow = out + (size_t)win * 6272;
        #pragma unroll
        for (int tt = 0; tt < 4; ++tt) {
            int tok = tt * 16 + l16;
            if (tok < NTOK) {
                #pragma unroll
                for (int mt = 0; mt < 2; ++mt) {
                    int o0 = wid * 32 + mt * 16 + lg * 4;
                    f32x4 w;
                    w.x = acco[mt][tt][0] + bpv[mt][0];
                    w.y = acco[mt][tt][1] + bpv[mt][1];
                    w.z = acco[mt][tt][2] + bpv[mt][2];
                    w.w = acco[mt][tt][3] + bpv[mt][3];
                    *(f32x4*)(ow + tok * 128 + o0) = w;
                }
            }
        }
    }
}

extern "C" void kernel_launch(void* const* d_in, const int* in_sizes, int n_in,
                              void* d_out, int out_size, void* d_ws, size_t ws_size,
                              hipStream_t stream)
{
    const float* x    = (const float*)d_in[0];
    const float* mask = (const float*)d_in[1];
    const float* Wq   = (const float*)d_in[2];
    const float* bq   = (const float*)d_in[3];
    const float* Wk   = (const float*)d_in[4];
    const float* bk   = (const float*)d_in[5];
    const float* Wv   = (const float*)d_in[6];
    const float* bv   = (const float*)d_in[7];
    const float* Wp   = (const float*)d_in[8];
    const float* bp   = (const float*)d_in[9];
    const float* rlb  = (const float*)d_in[10];
    short* ws = (short*)d_ws;
    short* cmb = ws + 81920;
    const size_t need = ((size_t)81920 + (size_t)16777216) * 2;
    const bool use_cmb = ws_size >= need;

    prep_w<<<64, 256, 0, stream>>>(Wq, Wk, Wv, Wp, rlb, ws);
    if (use_cmb) {
        prep_cmb<<<65536, 256, 0, stream>>>(mask, rlb, cmb);
        swin_fwd_p<<<768, 256, 49152, stream>>>(x, bq, bk, bv, bp,
            ws, ws + 16384, ws + 32768, ws + 49152, cmb, (float*)d_out);
    } else {
        swin_fwd_fb<<<16384, 256, 65536, stream>>>(x, mask, bq, bk, bv, bp,
            ws, ws + 16384, ws + 32768, ws + 49152, ws + 65536, (float*)d_out);
    }
}

// Round 11
// 621.697 us; speedup vs baseline: 1.2892x; 1.2892x over previous
//
#include <hip/hip_runtime.h>
#include <hip/hip_bf16.h>
#include <stdint.h>

#define NTOK 49
#define LOG2E 1.4426950408889634f
#define SCALE2 0.25507662683243807f   /* 32^-0.5 * log2(e) */

typedef __attribute__((ext_vector_type(4))) float f32x4;
typedef __attribute__((ext_vector_type(2))) unsigned int u32x2;
typedef __attribute__((ext_vector_type(4))) unsigned int u32x4;
typedef __attribute__((ext_vector_type(8))) short bfrag;
typedef __attribute__((ext_vector_type(4))) short s16x4;
typedef __attribute__((ext_vector_type(4))) float facc;

#define MFMA16(A,B,C) __builtin_amdgcn_mfma_f32_16x16x32_bf16(A,B,C,0,0,0)
#define EXP2(x) __builtin_amdgcn_exp2f(x)
#define MEMBAR() asm volatile("" ::: "memory")

__device__ __forceinline__ unsigned pk2bf(float a, float b) {
    unsigned r;
    asm("v_cvt_pk_bf16_f32 %0, %1, %2" : "=v"(r) : "v"(a), "v"(b));
    return r;
}
__device__ __forceinline__ short f2bf(float a) {
    unsigned ua = __builtin_bit_cast(unsigned, a);
    ua = ua + 0x7fffu + ((ua >> 16) & 1u);
    return (short)(ua >> 16);
}
__device__ __forceinline__ float bf2f(short s) {
    unsigned u = ((unsigned)(unsigned short)s) << 16;
    return __builtin_bit_cast(float, u);
}
__device__ __forceinline__ int sw256(int row, int cb) { return row * 256 + (cb ^ ((row & 7) << 4)); }
__device__ __forceinline__ int strip64(int row, int cb) { return row * 64 + (cb ^ (((row >> 1) & 3) << 4)); }
__device__ __forceinline__ int sw128v(int row, int cb) { return row * 128 + (cb ^ ((row & 7) << 4)); }

__global__ void prep_w(const float* __restrict__ Wq, const float* __restrict__ Wk,
                       const float* __restrict__ Wv, const float* __restrict__ Wp,
                       const float* __restrict__ relb, short* __restrict__ ws)
{
    int t = blockIdx.x * 256 + threadIdx.x;
    if (t >= 16384) return;
    int e = t & 7, lane = (t >> 3) & 63, ks = (t >> 9) & 3, tile = t >> 11;
    int row = tile * 16 + (lane & 15);
    int col = ks * 32 + (lane >> 4) * 8 + e;
    int src = row * 128 + col;
    ws[t]         = f2bf(Wq[src]);
    ws[16384 + t] = f2bf(Wk[src]);
    ws[32768 + t] = f2bf(Wv[src]);
    ws[49152 + t] = f2bf(Wp[src]);
    int e2 = t & 3, lane2 = (t >> 2) & 63, mt = (t >> 8) & 3, rt = (t >> 10) & 3, h = t >> 12;
    int r = rt * 16 + (lane2 & 15);
    int m = mt * 16 + (lane2 >> 4) * 4 + e2;
    float v = 0.f;
    if (r < NTOK && m < NTOK) {
        int idx = ((r / 7 - m / 7) + 6) * 13 + ((r % 7) - (m % 7) + 6);
        v = relb[idx * 4 + h] * LOG2E;
    }
    ws[65536 + t] = f2bf(v);
}

__global__ void prep_cmb(const float* __restrict__ mask, const float* __restrict__ relb,
                         short* __restrict__ cmb)
{
    int t = blockIdx.x * 256 + threadIdx.x;
    int e = t & 3, lane = (t >> 2) & 63, mt = (t >> 8) & 3, rt = (t >> 10) & 3;
    int h = (t >> 12) & 3, w = t >> 14;
    int r = rt * 16 + (lane & 15);
    int m = mt * 16 + (lane >> 4) * 4 + e;
    float v = -1e30f;
    if (r < NTOK && m < NTOK) {
        int idx = ((r / 7 - m / 7) + 6) * 13 + ((r % 7) - (m % 7) + 6);
        v = (mask[w * (NTOK * NTOK) + r * NTOK + m] + relb[idx * 4 + h]) * LOG2E;
    }
    cmb[t] = f2bf(v);
}

// persistent: 768 blocks (3/CU, 48K static LDS) × 21-22 windows.
// Round-8 passing structure + static LDS + split P1; cmb upfront, round-8
// prefetch pattern. MEMBARs at every strip reuse transition.
__global__ __launch_bounds__(256, 3) void swin_fwd_p(
    const float* __restrict__ x,
    const float* __restrict__ bq, const float* __restrict__ bk,
    const float* __restrict__ bv, const float* __restrict__ bp,
    const short* __restrict__ wqf, const short* __restrict__ wkf,
    const short* __restrict__ wvf, const short* __restrict__ wpf,
    const short* __restrict__ cmbf, float* __restrict__ out)
{
    __shared__ __align__(16) char smem[49152];
    char* xbuf = smem;
    char* attb = smem + 16384;

    const int b = blockIdx.x;
    const int tid = threadIdx.x;
    const int wid = tid >> 6;
    const int lane = tid & 63;
    const int l16 = lane & 15;
    const int lg = lane >> 4;
    char* wscr = smem + 16384 + wid * 8192;
    const int cnt = (b < 256) ? 22 : 21;

    // persistent biases (26 VGPRs)
    float bqv[2][4], bkv[2][4], bpv[2][4], bvv2[2];
    #pragma unroll
    for (int mt = 0; mt < 2; ++mt) {
        #pragma unroll
        for (int j = 0; j < 4; ++j) {
            int o = wid * 32 + mt * 16 + lg * 4 + j;
            bqv[mt][j] = bq[o]; bkv[mt][j] = bk[o]; bpv[mt][j] = bp[o];
        }
        bvv2[mt] = bv[wid * 32 + mt * 16 + l16];
    }

    // prologue: stage x(b); pad rows zeroed ONCE
    {
        f32x4 xp[7];
        const float* xw0 = x + (size_t)b * 6272;
        #pragma unroll
        for (int ii = 0; ii < 7; ++ii) {
            int i4 = ii * 256 + tid;
            if (i4 < 1568) xp[ii] = *(const f32x4*)(xw0 + i4 * 4);
        }
        #pragma unroll
        for (int ii = 0; ii < 7; ++ii) {
            int i4 = ii * 256 + tid;
            if (i4 < 1568) {
                int tok = i4 >> 5, col = (i4 & 31) * 4;
                u32x2 w; w.x = pk2bf(xp[ii].x, xp[ii].y); w.y = pk2bf(xp[ii].z, xp[ii].w);
                *(u32x2*)(xbuf + sw256(tok, col * 2)) = w;
            }
        }
        if (tid < 240) { u32x4 z = {0, 0, 0, 0}; *(u32x4*)(xbuf + 49 * 256 + tid * 16) = z; }
    }
    __syncthreads();

    #pragma unroll 1
    for (int it = 0; it < cnt; ++it) {
        const int win = b + it * 768;

        // ---- P1v: v-pass (av transient, 32 regs)
        {
            bfrag av[2][4];
            {
                const short* wv_i = wvf;
                asm volatile("" : "+s"(wv_i));
                #pragma unroll
                for (int mt = 0; mt < 2; ++mt)
                    #pragma unroll
                    for (int ks = 0; ks < 4; ++ks)
                        av[mt][ks] = *(const bfrag*)(wv_i + (((wid * 2 + mt) * 4 + ks) * 64 + lane) * 8);
            }
            #pragma unroll
            for (int nt = 0; nt < 4; ++nt) {
                bfrag bx[4];
                #pragma unroll
                for (int ks = 0; ks < 4; ++ks)
                    bx[ks] = *(const bfrag*)(xbuf + sw256(nt * 16 + l16, (ks * 32 + lg * 8) * 2));
                facc accv[2] = {{0,0,0,0},{0,0,0,0}};
                __builtin_amdgcn_s_setprio(1);
                #pragma unroll
                for (int ks = 0; ks < 4; ++ks)
                    #pragma unroll
                    for (int mt = 0; mt < 2; ++mt)
                        accv[mt] = MFMA16(bx[ks], av[mt][ks], accv[mt]);
                __builtin_amdgcn_s_setprio(0);
                #pragma unroll
                for (int mt = 0; mt < 2; ++mt) {
                    u32x2 wv2;
                    wv2.x = pk2bf(accv[mt][0] + bvv2[mt], accv[mt][1] + bvv2[mt]);
                    wv2.y = pk2bf(accv[mt][2] + bvv2[mt], accv[mt][3] + bvv2[mt]);
                    *(u32x2*)(wscr + 4096 + sw128v(mt * 16 + l16, nt * 32 + lg * 8)) = wv2;
                }
            }
        }
        MEMBAR();

        // ---- P1qk: q,k GEMMs (aq+ak transient, 64 regs)
        u32x2 kp[4][2];
        {
            bfrag aq[2][4], ak[2][4];
            {
                const short* wq_i = wqf; const short* wk_i = wkf;
                asm volatile("" : "+s"(wq_i), "+s"(wk_i));
                #pragma unroll
                for (int mt = 0; mt < 2; ++mt)
                    #pragma unroll
                    for (int ks = 0; ks < 4; ++ks) {
                        int fi = (((wid * 2 + mt) * 4 + ks) * 64 + lane) * 8;
                        aq[mt][ks] = *(const bfrag*)(wq_i + fi);
                        ak[mt][ks] = *(const bfrag*)(wk_i + fi);
                    }
            }
            #pragma unroll
            for (int nt = 0; nt < 4; ++nt) {
                bfrag bx[4];
                #pragma unroll
                for (int ks = 0; ks < 4; ++ks)
                    bx[ks] = *(const bfrag*)(xbuf + sw256(nt * 16 + l16, (ks * 32 + lg * 8) * 2));
                facc accq[2] = {{0,0,0,0},{0,0,0,0}};
                facc acck[2] = {{0,0,0,0},{0,0,0,0}};
                __builtin_amdgcn_s_setprio(1);
                #pragma unroll
                for (int ks = 0; ks < 4; ++ks)
                    #pragma unroll
                    for (int mt = 0; mt < 2; ++mt) {
                        accq[mt] = MFMA16(aq[mt][ks], bx[ks], accq[mt]);
                        acck[mt] = MFMA16(ak[mt][ks], bx[ks], acck[mt]);
                    }
                __builtin_amdgcn_s_setprio(0);
                int tok = nt * 16 + l16;
                #pragma unroll
                for (int mt = 0; mt < 2; ++mt) {
                    u32x2 wq2;
                    wq2.x = pk2bf((accq[mt][0] + bqv[mt][0]) * SCALE2, (accq[mt][1] + bqv[mt][1]) * SCALE2);
                    wq2.y = pk2bf((accq[mt][2] + bqv[mt][2]) * SCALE2, (accq[mt][3] + bqv[mt][3]) * SCALE2);
                    *(u32x2*)(wscr + strip64(tok, mt * 32 + lg * 8)) = wq2;
                    kp[nt][mt].x = pk2bf(acck[mt][0] + bkv[mt][0], acck[mt][1] + bkv[mt][1]);
                    kp[nt][mt].y = pk2bf(acck[mt][2] + bkv[mt][2], acck[mt][3] + bkv[mt][3]);
                }
            }
        }
        MEMBAR();   // q writes -> q reads
        bfrag qb[4];
        #pragma unroll
        for (int t = 0; t < 4; ++t)
            qb[t] = *(const bfrag*)(wscr + strip64(t * 16 + l16, lg * 16));
        MEMBAR();   // q reads -> k overwrite
        #pragma unroll
        for (int nt = 0; nt < 4; ++nt)
            #pragma unroll
            for (int mt = 0; mt < 2; ++mt)
                *(u32x2*)(wscr + strip64(nt * 16 + l16, mt * 32 + lg * 8)) = kp[nt][mt];
        MEMBAR();   // k writes -> k reads
        bfrag ka[4];
        #pragma unroll
        for (int t = 0; t < 4; ++t)
            ka[t] = *(const bfrag*)(wscr + strip64(t * 16 + l16, lg * 16));
        MEMBAR();   // k reads -> later P overwrite

        // combined-bias loads, all upfront (round-8 pattern)
        s16x4 b4r[4][4];
        {
            const short* cw = cmbf + ((size_t)((win & 1023) * 4 + wid) << 12);
            #pragma unroll
            for (int rt = 0; rt < 4; ++rt)
                #pragma unroll
                for (int mt = 0; mt < 4; ++mt)
                    b4r[rt][mt] = *(const s16x4*)(cw + ((rt * 4 + mt) << 8) + lane * 4);
        }

        // ---- P2: QK^T (S^T = k·qT)
        facc s[4][4];
        {
            __builtin_amdgcn_s_setprio(1);
            #pragma unroll
            for (int mt = 0; mt < 4; ++mt)
                #pragma unroll
                for (int rt = 0; rt < 4; ++rt) {
                    facc z = {0, 0, 0, 0};
                    s[mt][rt] = MFMA16(ka[mt], qb[rt], z);
                }
            __builtin_amdgcn_s_setprio(0);
        }

        // ---- P3: softmax (log2 domain); P half-A -> strip, half-B in regs
        float rs4[4];
        u32x2 pwB[4][2];
        {
            #pragma unroll
            for (int rt = 0; rt < 4; ++rt) {
                float lgt[4][4];
                float mx = -3e38f;
                #pragma unroll
                for (int mt = 0; mt < 4; ++mt)
                    #pragma unroll
                    for (int j = 0; j < 4; ++j) {
                        float v = s[mt][rt][j] + bf2f(b4r[rt][mt][j]);
                        lgt[mt][j] = v;
                        mx = fmaxf(mx, v);
                    }
                mx = fmaxf(mx, __shfl_xor(mx, 16));
                mx = fmaxf(mx, __shfl_xor(mx, 32));
                float sum = 0.f;
                u32x2 pw[4];
                #pragma unroll
                for (int mt = 0; mt < 4; ++mt) {
                    float p0 = EXP2(lgt[mt][0] - mx);
                    float p1 = EXP2(lgt[mt][1] - mx);
                    float p2 = EXP2(lgt[mt][2] - mx);
                    float p3 = EXP2(lgt[mt][3] - mx);
                    sum += (p0 + p1) + (p2 + p3);
                    pw[mt].x = pk2bf(p0, p1);
                    pw[mt].y = pk2bf(p2, p3);
                }
                sum += __shfl_xor(sum, 16);
                sum += __shfl_xor(sum, 32);
                rs4[rt] = __builtin_amdgcn_rcpf(sum);
                int r = rt * 16 + l16;
                *(u32x2*)(wscr + strip64(r, lg * 8)) = pw[0];
                *(u32x2*)(wscr + strip64(r, 32 + lg * 8)) = pw[1];
                pwB[rt][0] = pw[2]; pwB[rt][1] = pw[3];
            }
        }
        MEMBAR();   // P half-A writes -> PV reads

        // x(w+1) prefetch issued here (round-8 position region): hides under PV/B1
        f32x4 xr[7];
        if (it + 1 < cnt) {
            const float* xn = x + (size_t)(win + 768) * 6272;
            #pragma unroll
            for (int ii = 0; ii < 7; ++ii) {
                int i4 = ii * 256 + tid;
                if (i4 < 1568) xr[ii] = *(const f32x4*)(xn + i4 * 4);
            }
        }

        // ---- P4: PV swapped, two m-halves through the strip
        facc o2[2][4];
        #pragma unroll
        for (int ct = 0; ct < 2; ++ct)
            #pragma unroll
            for (int rt = 0; rt < 4; ++rt) o2[ct][rt] = (facc){0, 0, 0, 0};
        {
            bfrag avf[2], pb[4];
            #pragma unroll
            for (int ct = 0; ct < 2; ++ct)
                avf[ct] = *(const bfrag*)(wscr + 4096 + sw128v(ct * 16 + l16, lg * 16));
            #pragma unroll
            for (int rt = 0; rt < 4; ++rt)
                pb[rt] = *(const bfrag*)(wscr + strip64(rt * 16 + l16, lg * 16));
            __builtin_amdgcn_s_setprio(1);
            #pragma unroll
            for (int ct = 0; ct < 2; ++ct)
                #pragma unroll
                for (int rt = 0; rt < 4; ++rt)
                    o2[ct][rt] = MFMA16(avf[ct], pb[rt], o2[ct][rt]);
            __builtin_amdgcn_s_setprio(0);
        }
        MEMBAR();   // PV half-A reads -> half-B overwrite
        #pragma unroll
        for (int rt = 0; rt < 4; ++rt) {
            int r = rt * 16 + l16;
            *(u32x2*)(wscr + strip64(r, lg * 8)) = pwB[rt][0];
            *(u32x2*)(wscr + strip64(r, 32 + lg * 8)) = pwB[rt][1];
        }
        MEMBAR();   // half-B writes -> reads
        {
            bfrag avf[2], pb[4];
            #pragma unroll
            for (int ct = 0; ct < 2; ++ct)
                avf[ct] = *(const bfrag*)(wscr + 4096 + sw128v(ct * 16 + l16, 64 + lg * 16));
            #pragma unroll
            for (int rt = 0; rt < 4; ++rt)
                pb[rt] = *(const bfrag*)(wscr + strip64(rt * 16 + l16, lg * 16));
            __builtin_amdgcn_s_setprio(1);
            #pragma unroll
            for (int ct = 0; ct < 2; ++ct)
                #pragma unroll
                for (int rt = 0; rt < 4; ++rt)
                    o2[ct][rt] = MFMA16(avf[ct], pb[rt], o2[ct][rt]);
            __builtin_amdgcn_s_setprio(0);
        }
        // pack normalized att into regs
        u32x2 attw[2][4];
        #pragma unroll
        for (int ct = 0; ct < 2; ++ct)
            #pragma unroll
            for (int rt = 0; rt < 4; ++rt) {
                float sc = rs4[rt];
                attw[ct][rt].x = pk2bf(o2[ct][rt][0] * sc, o2[ct][rt][1] * sc);
                attw[ct][rt].y = pk2bf(o2[ct][rt][2] * sc, o2[ct][rt][3] * sc);
            }
        // proj weights (transient; in flight across B1)
        bfrag ap[2][4];
        {
            const short* wp_i = wpf;
            asm volatile("" : "+s"(wp_i));
            #pragma unroll
            for (int mt = 0; mt < 2; ++mt)
                #pragma unroll
                for (int ks = 0; ks < 4; ++ks)
                    ap[mt][ks] = *(const bfrag*)(wp_i + (((wid * 2 + mt) * 4 + ks) * 64 + lane) * 8);
        }
        __syncthreads();   // B1: all scratch/x reads done -> att + x(w+1) writes
        #pragma unroll
        for (int ct = 0; ct < 2; ++ct)
            #pragma unroll
            for (int rt = 0; rt < 4; ++rt)
                *(u32x2*)(attb + sw256(rt * 16 + l16, (wid * 32 + ct * 16 + lg * 4) * 2)) = attw[ct][rt];
        if (it + 1 < cnt) {
            #pragma unroll
            for (int ii = 0; ii < 7; ++ii) {
                int i4 = ii * 256 + tid;
                if (i4 < 1568) {
                    int tok = i4 >> 5, col = (i4 & 31) * 4;
                    u32x2 w; w.x = pk2bf(xr[ii].x, xr[ii].y); w.y = pk2bf(xr[ii].z, xr[ii].w);
                    *(u32x2*)(xbuf + sw256(tok, col * 2)) = w;
                }
            }
        }
        __syncthreads();   // B2: att + x staged

        // ---- P5: proj D[o][tok] = Wp · att^T; contiguous f32x4 stores
        {
            facc acco[2][4];
            #pragma unroll
            for (int mt = 0; mt < 2; ++mt)
                #pragma unroll
                for (int tt = 0; tt < 4; ++tt) acco[mt][tt] = (facc){0, 0, 0, 0};
            #pragma unroll
            for (int tt = 0; tt < 4; ++tt) {
                bfrag ba[4];
                #pragma unroll
                for (int ks = 0; ks < 4; ++ks)
                    ba[ks] = *(const bfrag*)(attb + sw256(tt * 16 + l16, (ks * 32 + lg * 8) * 2));
                __builtin_amdgcn_s_setprio(1);
                #pragma unroll
                for (int ks = 0; ks < 4; ++ks)
                    #pragma unroll
                    for (int mt = 0; mt < 2; ++mt)
                        acco[mt][tt] = MFMA16(ap[mt][ks], ba[ks], acco[mt][tt]);
                __builtin_amdgcn_s_setprio(0);
            }
            float* ow = out + (size_t)win * 6272;
            #pragma unroll
            for (int tt = 0; tt < 4; ++tt) {
                int tok = tt * 16 + l16;
                if (tok < NTOK) {
                    #pragma unroll
                    for (int mt = 0; mt < 2; ++mt) {
                        int o0 = wid * 32 + mt * 16 + lg * 4;
                        f32x4 w;
                        w.x = acco[mt][tt][0] + bpv[mt][0];
                        w.y = acco[mt][tt][1] + bpv[mt][1];
                        w.z = acco[mt][tt][2] + bpv[mt][2];
                        w.w = acco[mt][tt][3] + bpv[mt][3];
                        *(f32x4*)(ow + tok * 128 + o0) = w;
                    }
                }
            }
        }
        __syncthreads();   // B3: P5 att reads done -> next window scratch reuse
    }
}

// fallback (no cmb): round-6 structure, grid 16384 (barrier-protected)
__global__ __launch_bounds__(256, 2) void swin_fwd_fb(
    const float* __restrict__ x, const float* __restrict__ mask,
    const float* __restrict__ bq, const float* __restrict__ bk,
    const float* __restrict__ bv, const float* __restrict__ bp,
    const short* __restrict__ wqf, const short* __restrict__ wkf,
    const short* __restrict__ wvf, const short* __restrict__ wpf,
    const short* __restrict__ rbf, float* __restrict__ out)
{
    extern __shared__ char dsm[];
    char* qbuf  = dsm;
    char* kbuf  = dsm + 16384;
    char* vtbuf = dsm + 32768;
    char* r4    = dsm + 49152;

    const int win = blockIdx.x;
    const int tid = threadIdx.x;
    const int wid = tid >> 6;
    const int lane = tid & 63;
    const int l16 = lane & 15;
    const int lg = lane >> 4;

    {
        const float* xw = x + (size_t)win * 6272;
        #pragma unroll
        for (int i = 0; i < 7; ++i) {
            int i4 = i * 256 + tid;
            if (i4 < 1568) {
                f32x4 f = *(const f32x4*)(xw + i4 * 4);
                int tok = i4 >> 5, col = (i4 & 31) * 4;
                u32x2 w; w.x = pk2bf(f.x, f.y); w.y = pk2bf(f.z, f.w);
                *(u32x2*)(r4 + sw256(tok, col * 2)) = w;
            }
        }
        if (tid < 240) { u32x4 z = {0, 0, 0, 0}; *(u32x4*)(r4 + 49 * 256 + tid * 16) = z; }
    }
    bfrag aq[2][4], ak[2][4], av[2][4];
    float bqv[2][4], bkv[2][4], bvv2[2];
    #pragma unroll
    for (int mt = 0; mt < 2; ++mt) {
        #pragma unroll
        for (int ks = 0; ks < 4; ++ks) {
            int fi = (((wid * 2 + mt) * 4 + ks) * 64 + lane) * 8;
            aq[mt][ks] = *(const bfrag*)(wqf + fi);
            ak[mt][ks] = *(const bfrag*)(wkf + fi);
            av[mt][ks] = *(const bfrag*)(wvf + fi);
        }
        #pragma unroll
        for (int j = 0; j < 4; ++j) {
            int o = wid * 32 + mt * 16 + lg * 4 + j;
            bqv[mt][j] = bq[o]; bkv[mt][j] = bk[o];
        }
        bvv2[mt] = bv[wid * 32 + mt * 16 + l16];
    }
    __syncthreads();

    {
        #pragma unroll
        for (int nt = 0; nt < 4; ++nt) {
            bfrag bx[4];
            #pragma unroll
            for (int ks = 0; ks < 4; ++ks)
                bx[ks] = *(const bfrag*)(r4 + sw256(nt * 16 + l16, (ks * 32 + lg * 8) * 2));
            facc accq[2] = {{0,0,0,0},{0,0,0,0}};
            facc acck[2] = {{0,0,0,0},{0,0,0,0}};
            facc accv[2] = {{0,0,0,0},{0,0,0,0}};
            #pragma unroll
            for (int ks = 0; ks < 4; ++ks)
                #pragma unroll
                for (int mt = 0; mt < 2; ++mt) {
                    accq[mt] = MFMA16(aq[mt][ks], bx[ks], accq[mt]);
                    acck[mt] = MFMA16(ak[mt][ks], bx[ks], acck[mt]);
                    accv[mt] = MFMA16(bx[ks], av[mt][ks], accv[mt]);
                }
            int tok = nt * 16 + l16;
            #pragma unroll
            for (int mt = 0; mt < 2; ++mt) {
                int o0 = wid * 32 + mt * 16 + lg * 4;
                u32x2 wq2, wk2, wv2;
                wq2.x = pk2bf((accq[mt][0] + bqv[mt][0]) * SCALE2, (accq[mt][1] + bqv[mt][1]) * SCALE2);
                wq2.y = pk2bf((accq[mt][2] + bqv[mt][2]) * SCALE2, (accq[mt][3] + bqv[mt][3]) * SCALE2);
                wk2.x = pk2bf(acck[mt][0] + bkv[mt][0], acck[mt][1] + bkv[mt][1]);
                wk2.y = pk2bf(acck[mt][2] + bkv[mt][2], acck[mt][3] + bkv[mt][3]);
                *(u32x2*)(qbuf + sw256(tok, o0 * 2)) = wq2;
                *(u32x2*)(kbuf + sw256(tok, o0 * 2)) = wk2;
                wv2.x = pk2bf(accv[mt][0] + bvv2[mt], accv[mt][1] + bvv2[mt]);
                wv2.y = pk2bf(accv[mt][2] + bvv2[mt], accv[mt][3] + bvv2[mt]);
                *(u32x2*)(vtbuf + sw128v(wid * 32 + mt * 16 + l16, (nt * 16 + lg * 4) * 2)) = wv2;
            }
        }
    }
    MEMBAR();
    facc s[4][4];
    {
        bfrag ka[4], qb[4];
        int cb = (wid * 32 + lg * 8) * 2;
        #pragma unroll
        for (int t = 0; t < 4; ++t) {
            ka[t] = *(const bfrag*)(kbuf + sw256(t * 16 + l16, cb));
            qb[t] = *(const bfrag*)(qbuf + sw256(t * 16 + l16, cb));
        }
        #pragma unroll
        for (int mt = 0; mt < 4; ++mt)
            #pragma unroll
            for (int rt = 0; rt < 4; ++rt) {
                facc z = {0, 0, 0, 0};
                s[mt][rt] = MFMA16(ka[mt], qb[rt], z);
            }
    }
    __syncthreads();
    {
        const float* mw = mask + (size_t)(win & 1023) * (NTOK * NTOK);
        #pragma unroll
        for (int i = 0; i < 16; ++i) {
            int flat = i * 256 + tid;
            int r = flat >> 6, m = flat & 63;
            float v = -1e30f;
            if (r < NTOK && m < NTOK) v = mw[r * 49 + m] * LOG2E;
            *(float*)(r4 + sw256(r, m * 4)) = v;
        }
    }
    __syncthreads();
    float rs4[4];
    {
        #pragma unroll
        for (int rt = 0; rt < 4; ++rt) {
            int r = rt * 16 + l16;
            float lgt[4][4];
            float mx = -3e38f;
            #pragma unroll
            for (int mt = 0; mt < 4; ++mt) {
                s16x4 b4 = *(const s16x4*)(rbf + ((wid * 16 + rt * 4 + mt) * 64 + lane) * 4);
                f32x4 mk = *(const f32x4*)(r4 + sw256(r, (mt * 16 + lg * 4) * 4));
                #pragma unroll
                for (int j = 0; j < 4; ++j) {
                    float v = s[mt][rt][j] + bf2f(b4[j]) + mk[j];
                    lgt[mt][j] = v;
                    mx = fmaxf(mx, v);
                }
            }
            mx = fmaxf(mx, __shfl_xor(mx, 16));
            mx = fmaxf(mx, __shfl_xor(mx, 32));
            float sum = 0.f;
            u32x2 pw[4];
            #pragma unroll
            for (int mt = 0; mt < 4; ++mt) {
                float p0 = EXP2(lgt[mt][0] - mx);
                float p1 = EXP2(lgt[mt][1] - mx);
                float p2 = EXP2(lgt[mt][2] - mx);
                float p3 = EXP2(lgt[mt][3] - mx);
                sum += (p0 + p1) + (p2 + p3);
                pw[mt].x = pk2bf(p0, p1);
                pw[mt].y = pk2bf(p2, p3);
            }
            sum += __shfl_xor(sum, 16);
            sum += __shfl_xor(sum, 32);
            rs4[rt] = __builtin_amdgcn_rcpf(sum);
            #pragma unroll
            for (int mt = 0; mt < 4; ++mt) {
                int mb = mt * 32 + lg * 8;
                *(u32x2*)(dsm + ((mb >> 6) << 14) + r * 256 + ((wid * 64 + (mb & 63)) ^ ((r & 7) << 4))) = pw[mt];
            }
        }
    }
    MEMBAR();
    facc o2[2][4];
    {
        #pragma unroll
        for (int ct = 0; ct < 2; ++ct)
            #pragma unroll
            for (int rt = 0; rt < 4; ++rt) o2[ct][rt] = (facc){0, 0, 0, 0};
        #pragma unroll
        for (int ks = 0; ks < 2; ++ks) {
            bfrag avf[2], pb[4];
            #pragma unroll
            for (int ct = 0; ct < 2; ++ct)
                avf[ct] = *(const bfrag*)(vtbuf + sw128v(wid * 32 + ct * 16 + l16, (ks * 32 + lg * 8) * 2));
            #pragma unroll
            for (int rt = 0; rt < 4; ++rt) {
                int mb = ks * 64 + lg * 16, r = rt * 16 + l16;
                pb[rt] = *(const bfrag*)(dsm + ((mb >> 6) << 14) + r * 256 + ((wid * 64 + (mb & 63)) ^ ((r & 7) << 4)));
            }
            #pragma unroll
            for (int ct = 0; ct < 2; ++ct)
                #pragma unroll
                for (int rt = 0; rt < 4; ++rt)
                    o2[ct][rt] = MFMA16(avf[ct], pb[rt], o2[ct][rt]);
        }
    }
    bfrag ap[2][4];
    float bpv[2][4];
    #pragma unroll
    for (int mt = 0; mt < 2; ++mt) {
        #pragma unroll
        for (int ks = 0; ks < 4; ++ks)
            ap[mt][ks] = *(const bfrag*)(wpf + (((wid * 2 + mt) * 4 + ks) * 64 + lane) * 8);
        #pragma unroll
        for (int j = 0; j < 4; ++j)
            bpv[mt][j] = bp[wid * 32 + mt * 16 + lg * 4 + j];
    }
    __syncthreads();
    {
        #pragma unroll
        for (int ct = 0; ct < 2; ++ct) {
            int c0 = wid * 32 + ct * 16 + lg * 4;
            #pragma unroll
            for (int rt = 0; rt < 4; ++rt) {
                int r = rt * 16 + l16;
                float sc = rs4[rt];
                u32x2 w;
                w.x = pk2bf(o2[ct][rt][0] * sc, o2[ct][rt][1] * sc);
                w.y = pk2bf(o2[ct][rt][2] * sc, o2[ct][rt][3] * sc);
                *(u32x2*)(r4 + sw256(r, c0 * 2)) = w;
            }
        }
    }
    __syncthreads();
    {
        facc acco[2][4];
        #pragma unroll
        for (int mt = 0; mt < 2; ++mt)
            #pragma unroll
            for (int tt = 0; tt < 4; ++tt) acco[mt][tt] = (facc){0, 0, 0, 0};
        #pragma unroll
        for (int tt = 0; tt < 4; ++tt) {
            bfrag ba[4];
            #pragma unroll
            for (int ks = 0; ks < 4; ++ks)
                ba[ks] = *(const bfrag*)(r4 + sw256(tt * 16 + l16, (ks * 32 + lg * 8) * 2));
            #pragma unroll
            for (int ks = 0; ks < 4; ++ks)
                #pragma unroll
                for (int mt = 0; mt < 2; ++mt)
                    acco[mt][tt] = MFMA16(ap[mt][ks], ba[ks], acco[mt][tt]);
        }
        float* ow = out + (size_t)win * 6272;
        #pragma unroll
        for (int tt = 0; tt < 4; ++tt) {
            int tok = tt * 16 + l16;
            if (tok < NTOK) {
                #pragma unroll
                for (int mt = 0; mt < 2; ++mt) {
                    int o0 = wid * 32 + mt * 16 + lg * 4;
                    f32x4 w;
                    w.x = acco[mt][tt][0] + bpv[mt][0];
                    w.y = acco[mt][tt][1] + bpv[mt][1];
                    w.z = acco[mt][tt][2] + bpv[mt][2];
                    w.w = acco[mt][tt][3] + bpv[mt][3];
                    *(f32x4*)(ow + tok * 128 + o0) = w;
                }
            }
        }
    }
}

extern "C" void kernel_launch(void* const* d_in, const int* in_sizes, int n_in,
                              void* d_out, int out_size, void* d_ws, size_t ws_size,
                              hipStream_t stream)
{
    const float* x    = (const float*)d_in[0];
    const float* mask = (const float*)d_in[1];
    const float* Wq   = (const float*)d_in[2];
    const float* bq   = (const float*)d_in[3];
    const float* Wk   = (const float*)d_in[4];
    const float* bk   = (const float*)d_in[5];
    const float* Wv   = (const float*)d_in[6];
    const float* bv   = (const float*)d_in[7];
    const float* Wp   = (const float*)d_in[8];
    const float* bp   = (const float*)d_in[9];
    const float* rlb  = (const float*)d_in[10];
    short* ws = (short*)d_ws;
    short* cmb = ws + 81920;
    const size_t need = ((size_t)81920 + (size_t)16777216) * 2;
    const bool use_cmb = ws_size >= need;

    prep_w<<<64, 256, 0, stream>>>(Wq, Wk, Wv, Wp, rlb, ws);
    if (use_cmb) {
        prep_cmb<<<65536, 256, 0, stream>>>(mask, rlb, cmb);
        swin_fwd_p<<<768, 256, 0, stream>>>(x, bq, bk, bv, bp,
            ws, ws + 16384, ws + 32768, ws + 49152, cmb, (float*)d_out);
    } else {
        swin_fwd_fb<<<16384, 256, 65536, stream>>>(x, mask, bq, bk, bv, bp,
            ws, ws + 16384, ws + 32768, ws + 49152, ws + 65536, (float*)d_out);
    }
}